// Round 1
// baseline (1395.470 us; speedup 1.0000x reference)
//
#include <hip/hip_runtime.h>
#include <math.h>

#define Bb 2
#define Tt 1024
#define Cc 1024
#define Hh 16
#define Dd 64
#define Mm (Bb*Tt)
#define DECAY_SCALE (-0.6065306597126334f)
#define GN_EPS (64e-5f)

struct GemmDesc {
  const float* A;      // used when mixrow < 0 (row stride = K)
  const float* W;      // (N, K) row-major
  float* out;          // (M, N) row-major
  const float* bias;   // per-n bias or nullptr
  int N, K;
  int mixrow;          // >=0: A = token-shift mix of hidden_states with x_mix[mixrow]
  int ep;              // 0 none, 1 tanh, 2 sigmoid(x+bias?), 3 DECAY*sigmoid(x+bias)
};

__device__ __forceinline__ float4 ld4(const float* p){ return *reinterpret_cast<const float4*>(p); }
__device__ __forceinline__ float sigmf(float x){ return 1.f/(1.f+expf(-x)); }

__device__ __forceinline__ float wredsum(float x){
  #pragma unroll
  for (int off=32; off>0; off>>=1) x += __shfl_xor(x, off);
  return x;
}

#define BM 64
#define BN 128
#define BK 32

// out[m,n] = sum_k A[m,k]*W[n,k]; blockIdx.z selects descriptor (batched launches).
__global__ __launch_bounds__(256) void gemm_kernel(
    GemmDesc d0, GemmDesc d1, GemmDesc d2, GemmDesc d3,
    const float* __restrict__ xmix, const float* __restrict__ hs)
{
  GemmDesc d = (blockIdx.z==0)?d0:(blockIdx.z==1)?d1:(blockIdx.z==2)?d2:d3;
  const int n0 = blockIdx.x * BN;
  if (n0 >= d.N) return;            // block-uniform
  const int m0 = blockIdx.y * BM;
  const int tid = threadIdx.x;
  __shared__ float As[BK][BM+4];
  __shared__ float Bs[BK][BN+4];
  const int ty = tid >> 4, tx = tid & 15;

  float acc[4][8];
  #pragma unroll
  for (int i=0;i<4;++i)
    #pragma unroll
    for (int j=0;j<8;++j) acc[i][j]=0.f;

  const int K = d.K;
  const int nt = K / BK;
  const float* mrow = (d.mixrow >= 0) ? (xmix + (size_t)d.mixrow * Cc) : nullptr;
  float4 pa[2], pb[4];

  auto load_tile = [&](int kt){
    const int kbase = kt * BK;
    #pragma unroll
    for (int u=0;u<2;++u){
      const int li = tid + u*256;
      const int ar = li >> 3;
      const int kk = ((li & 7) << 2) + kbase;
      const int gm = m0 + ar;
      if (mrow){
        float4 h0 = ld4(hs + (size_t)gm*Cc + kk);
        float4 mx = ld4(mrow + kk);
        float4 hp = make_float4(0.f,0.f,0.f,0.f);
        if ((gm & (Tt-1)) != 0) hp = ld4(hs + (size_t)(gm-1)*Cc + kk);
        pa[u].x = h0.x + (hp.x - h0.x)*mx.x;
        pa[u].y = h0.y + (hp.y - h0.y)*mx.y;
        pa[u].z = h0.z + (hp.z - h0.z)*mx.z;
        pa[u].w = h0.w + (hp.w - h0.w)*mx.w;
      } else {
        pa[u] = ld4(d.A + (size_t)gm*K + kk);
      }
    }
    #pragma unroll
    for (int u=0;u<4;++u){
      const int li = tid + u*256;
      const int br = li >> 3;
      const int kk = ((li & 7) << 2) + kbase;
      const int gn = n0 + br;
      pb[u] = (gn < d.N) ? ld4(d.W + (size_t)gn*K + kk) : make_float4(0.f,0.f,0.f,0.f);
    }
  };

  load_tile(0);
  for (int kt=0; kt<nt; ++kt){
    __syncthreads();
    #pragma unroll
    for (int u=0;u<2;++u){
      const int li = tid + u*256;
      const int ar = li >> 3;
      const int kc = (li & 7) << 2;
      As[kc+0][ar] = pa[u].x; As[kc+1][ar] = pa[u].y;
      As[kc+2][ar] = pa[u].z; As[kc+3][ar] = pa[u].w;
    }
    #pragma unroll
    for (int u=0;u<4;++u){
      const int li = tid + u*256;
      const int br = li >> 3;
      const int kc = (li & 7) << 2;
      Bs[kc+0][br] = pb[u].x; Bs[kc+1][br] = pb[u].y;
      Bs[kc+2][br] = pb[u].z; Bs[kc+3][br] = pb[u].w;
    }
    __syncthreads();
    if (kt+1 < nt) load_tile(kt+1);
    #pragma unroll
    for (int kk=0;kk<BK;++kk){
      const float4 a0 = *(const float4*)&As[kk][ty<<2];
      const float4 b0 = *(const float4*)&Bs[kk][tx<<3];
      const float4 b1 = *(const float4*)&Bs[kk][(tx<<3)+4];
      const float av[4] = {a0.x,a0.y,a0.z,a0.w};
      const float bv[8] = {b0.x,b0.y,b0.z,b0.w,b1.x,b1.y,b1.z,b1.w};
      #pragma unroll
      for (int i=0;i<4;++i)
        #pragma unroll
        for (int j=0;j<8;++j)
          acc[i][j] = fmaf(av[i], bv[j], acc[i][j]);
    }
  }

  const int ep = d.ep;
  #pragma unroll
  for (int i=0;i<4;++i){
    const int gm = m0 + (ty<<2) + i;
    float* orow = d.out + (size_t)gm * d.N;
    #pragma unroll
    for (int j=0;j<8;++j){
      const int gn = n0 + (tx<<3) + j;
      if (gn < d.N){
        float x = acc[i][j];
        if (ep==1) x = tanhf(x);
        else if (ep==2){ if (d.bias) x += d.bias[gn]; x = sigmf(x); }
        else if (ep==3){ x += d.bias[gn]; x = DECAY_SCALE * sigmf(x); }
        orow[gn] = x;
      }
    }
  }
}

// Per-(token,head) wave: kk = normalize(k0*k_k); v = lerp(v0, v_first, sv); kfin.
__global__ __launch_bounds__(256) void head_prep(
    float* __restrict__ kbuf,        // in: k0, out: kfin
    const float* __restrict__ abuf,  // sigmoid a
    float* __restrict__ kkbuf,       // in: sv (v-lora sigmoid), out: kk normalized
    float* __restrict__ vbuf,        // in: v0, out: v
    const float* __restrict__ vfirst,
    const float* __restrict__ k_k, const float* __restrict__ k_a)
{
  const int gid = blockIdx.x*4 + (threadIdx.x>>6);
  const int e = threadIdx.x & 63;
  const int m = gid >> 4;
  const int h = gid & 15;
  const int c = h*Dd + e;
  const size_t idx = (size_t)m*Cc + c;
  const float kv0 = kbuf[idx];
  const float kku = kv0 * k_k[c];
  const float ss  = wredsum(kku*kku);
  const float kkn = kku / fmaxf(sqrtf(ss), 1e-12f);
  const float sv  = kkbuf[idx];
  const float vf  = vfirst[idx];
  const float v0  = vbuf[idx];
  const float av  = abuf[idx];
  kkbuf[idx] = kkn;
  vbuf[idx]  = v0 + sv*(vf - v0);
  kbuf[idx]  = kv0 * (1.f + (av - 1.f)*k_a[c]);
}

// Sequential scan: one block per (b,h); 4 waves; wave q owns columns [16q,16q+16),
// lane's 4 row-groups reduced with shfl_xor. S[d][e] in regs (16/thread).
#define SK(d) ((d) + ((d)>>4))
__global__ __launch_bounds__(256) void scan_kernel(
    const float* __restrict__ wl, const float* __restrict__ kb,
    const float* __restrict__ vb, const float* __restrict__ rb,
    const float* __restrict__ kkb, const float* __restrict__ ab,
    float* __restrict__ outp)
{
  const int bh = blockIdx.x;
  const int b = bh >> 4, h = bh & 15;
  const int tid  = threadIdx.x;
  const int wave = tid >> 6;
  const int lane = tid & 63;
  const int el = lane & 15;
  const int dg = lane >> 4;
  const int e  = (wave<<4) + el;
  const int dgs = dg * 17;          // skewed LDS base for row-group reads

  __shared__ float2 A2[2][68];      // {law=-kk*ew, ew}
  __shared__ float4 Q4[2][68];      // {b=kk*a, k, r, -}
  __shared__ float  LV[2][64];      // v

  float S[16];
  #pragma unroll
  for (int j=0;j<16;++j) S[j]=0.f;

  const size_t base = ((size_t)b*Tt)*Cc + h*Dd;

  // stage t=0 directly
  {
    const size_t i0 = base + lane;
    if (wave==0){
      float w0 = wl[i0], kkv = kkb[i0], av = ab[i0];
      float ew = expf(w0);
      A2[0][SK(lane)] = make_float2(-kkv*ew, ew);
      Q4[0][SK(lane)].x = kkv*av;
    } else if (wave==1){
      Q4[0][SK(lane)].y = kb[i0];
      Q4[0][SK(lane)].z = rb[i0];
    } else if (wave==2){
      LV[0][lane] = vb[i0];
    }
  }
  // prefetch t=1 into regA (depth-2 pipeline: regA = t+1 data, regB = t+2 loads)
  float a0=0,a1=0,a2=0,a3=0,a4=0,a5=0;
  {
    const size_t ni = base + (size_t)1*Cc + lane;
    if (wave==0){ a0 = wl[ni]; a1 = kkb[ni]; a2 = ab[ni]; }
    else if (wave==1){ a3 = kb[ni]; a4 = rb[ni]; }
    else if (wave==2){ a5 = vb[ni]; }
  }
  __syncthreads();

  for (int t=0; t<Tt; ++t){
    const int cur = t & 1, nxt = cur ^ 1;
    float b0=0,b1=0,b2=0,b3=0,b4=0,b5=0;
    if (t+2 < Tt){
      const size_t ni = base + (size_t)(t+2)*Cc + lane;
      if (wave==0){ b0 = wl[ni]; b1 = kkb[ni]; b2 = ab[ni]; }
      else if (wave==1){ b3 = kb[ni]; b4 = rb[ni]; }
      else if (wave==2){ b5 = vb[ni]; }
    }
    const float ve = LV[cur][e];
    float ta = 0.f;
    #pragma unroll
    for (int j=0;j<16;++j){
      const float2 q = A2[cur][dgs + j];
      ta = fmaf(q.x, S[j], ta);   // a_rec^T (D*S_old)
      S[j] *= q.y;                // decay
    }
    ta += __shfl_xor(ta, 16);
    ta += __shfl_xor(ta, 32);
    float oe = 0.f;
    #pragma unroll
    for (int j=0;j<16;++j){
      const float4 q = Q4[cur][dgs + j];
      S[j] = fmaf(q.x, ta, fmaf(q.y, ve, S[j]));  // + b*ta + k*v
      oe = fmaf(q.z, S[j], oe);                   // r^T S
    }
    oe += __shfl_xor(oe, 16);
    oe += __shfl_xor(oe, 32);
    if (dg == 0) outp[base + (size_t)t*Cc + e] = oe;
    if (t+1 < Tt){
      if (wave==0){
        float ew = expf(a0);
        A2[nxt][SK(lane)] = make_float2(-a1*ew, ew);
        Q4[nxt][SK(lane)].x = a1*a2;
      } else if (wave==1){
        Q4[nxt][SK(lane)].y = a3;
        Q4[nxt][SK(lane)].z = a4;
      } else if (wave==2){
        LV[nxt][lane] = a5;
      }
    }
    __syncthreads();
    a0=b0; a1=b1; a2=b2; a3=b3; a4=b4; a5=b5;
  }
}

// GroupNorm per head + correction + g gating -> o_pre
__global__ __launch_bounds__(256) void epilogue_kernel(
    const float* __restrict__ att, const float* __restrict__ rbuf,
    const float* __restrict__ kbuf, const float* __restrict__ vbuf,
    const float* __restrict__ gbuf,
    const float* __restrict__ r_k, const float* __restrict__ gn_w,
    const float* __restrict__ gn_b, float* __restrict__ opre)
{
  const int gid = blockIdx.x*4 + (threadIdx.x>>6);
  const int e = threadIdx.x & 63;
  const int m = gid >> 4;
  const int h = gid & 15;
  const int c = h*Dd + e;
  const size_t idx = (size_t)m*Cc + c;
  const float x  = att[idx];
  const float mu = wredsum(x) * (1.f/Dd);
  const float xd = x - mu;
  const float var = wredsum(xd*xd) * (1.f/Dd);
  const float og = xd * (1.f/sqrtf(var + GN_EPS)) * gn_w[c] + gn_b[c];
  const float rv = rbuf[idx], kv = kbuf[idx], vv = vbuf[idx];
  const float cd = wredsum(rv*kv*r_k[c]);
  opre[idx] = (og + cd*vv) * gbuf[idx];
}

extern "C" void kernel_launch(void* const* d_in, const int* in_sizes, int n_in,
                              void* d_out, int out_size, void* d_ws, size_t ws_size,
                              hipStream_t stream)
{
  (void)in_sizes; (void)n_in; (void)out_size; (void)ws_size;
  const float* hs     = (const float*)d_in[0];
  const float* vfirst = (const float*)d_in[1];
  const float* xmix   = (const float*)d_in[2];
  const float* k_k    = (const float*)d_in[3];
  const float* k_a    = (const float*)d_in[4];
  const float* r_k    = (const float*)d_in[5];
  const float* W_r    = (const float*)d_in[6];
  const float* W_k    = (const float*)d_in[7];
  const float* W_v    = (const float*)d_in[8];
  const float* W_o    = (const float*)d_in[9];
  const float* w_A    = (const float*)d_in[10];
  const float* w_B    = (const float*)d_in[11];
  const float* w_b    = (const float*)d_in[12];
  const float* a_A    = (const float*)d_in[13];
  const float* a_B    = (const float*)d_in[14];
  const float* a_b    = (const float*)d_in[15];
  const float* v_A    = (const float*)d_in[16];
  const float* v_B    = (const float*)d_in[17];
  const float* v_b    = (const float*)d_in[18];
  const float* g_A    = (const float*)d_in[19];
  const float* g_B    = (const float*)d_in[20];
  const float* gn_w   = (const float*)d_in[21];
  const float* gn_b   = (const float*)d_in[22];
  float* out = (float*)d_out;
  float* ws  = (float*)d_ws;

  const size_t MC = (size_t)Mm * Cc;
  float* Br   = ws;            // r
  float* Bw   = ws + MC;       // w log-decay  -> later o_pre
  float* Bk   = ws + 2*MC;     // k0 -> kfin
  float* Bkk  = ws + 3*MC;     // sv -> kk
  float* Bv   = ws + 4*MC;     // v0 -> v
  float* Ba   = ws + 5*MC;     // a (sigmoid)
  float* Batt = ws + 6*MC;     // scan output
  float* Bg   = ws + 7*MC;     // g
  float* T1w  = ws + 8*MC;
  float* T1a  = T1w + (size_t)Mm*64;
  float* T1v  = T1a + (size_t)Mm*64;
  float* T1g  = T1v + (size_t)Mm*64;   // Mm*160

  dim3 blk(256,1,1);

  // L1: big projections r, k0, v0 (batched over z)
  GemmDesc dr{nullptr, W_r, Br, nullptr, Cc, Cc, 0, 0};
  GemmDesc dk{nullptr, W_k, Bk, nullptr, Cc, Cc, 2, 0};
  GemmDesc dv{nullptr, W_v, Bv, nullptr, Cc, Cc, 3, 0};
  gemm_kernel<<<dim3(8,32,3), blk, 0, stream>>>(dr,dk,dv,dr, xmix, hs);

  // L2: LoRA stage-1 (w: tanh; a: none; v: none; g: sigmoid)
  GemmDesc s1w{nullptr, w_A, T1w, nullptr, 64, Cc, 1, 1};
  GemmDesc s1a{nullptr, a_A, T1a, nullptr, 64, Cc, 4, 0};
  GemmDesc s1v{nullptr, v_A, T1v, nullptr, 64, Cc, 3, 0};
  GemmDesc s1g{nullptr, g_A, T1g, nullptr, 160, Cc, 5, 2};
  gemm_kernel<<<dim3(2,32,4), blk, 0, stream>>>(s1w,s1a,s1v,s1g, xmix, hs);

  // L3: LoRA stage-2
  GemmDesc s2w{T1w, w_B, Bw,  w_b,    Cc, 64,  -1, 3};
  GemmDesc s2a{T1a, a_B, Ba,  a_b,    Cc, 64,  -1, 2};
  GemmDesc s2v{T1v, v_B, Bkk, v_b,    Cc, 64,  -1, 2};
  GemmDesc s2g{T1g, g_B, Bg,  nullptr,Cc, 160, -1, 0};
  gemm_kernel<<<dim3(8,32,4), blk, 0, stream>>>(s2w,s2a,s2v,s2g, xmix, hs);

  // L4: per-head prep (kk normalize, v lerp, kfin)
  head_prep<<<dim3(Mm*Hh/4), blk, 0, stream>>>(Bk, Ba, Bkk, Bv, vfirst, k_k, k_a);

  // L5: sequential scan
  scan_kernel<<<dim3(Bb*Hh), blk, 0, stream>>>(Bw, Bk, Bv, Br, Bkk, Ba, Batt);

  // L6: groupnorm + corr + g -> o_pre (reuse Bw)
  epilogue_kernel<<<dim3(Mm*Hh/4), blk, 0, stream>>>(Batt, Br, Bk, Bv, Bg,
                                                     r_k, gn_w, gn_b, Bw);

  // L7: output projection
  GemmDesc doo{Bw, W_o, out, nullptr, Cc, Cc, -1, 0};
  gemm_kernel<<<dim3(8,32,1), blk, 0, stream>>>(doo,doo,doo,doo, xmix, hs);
}

// Round 2
// 1054.046 us; speedup vs baseline: 1.3239x; 1.3239x over previous
//
#include <hip/hip_runtime.h>
#include <math.h>

#define Bb 2
#define Tt 1024
#define Cc 1024
#define Hh 16
#define Dd 64
#define Mm (Bb*Tt)
#define DECAY_SCALE (-0.6065306597126334f)
#define GN_EPS (64e-5f)

struct GemmDesc {
  const float* A;      // used when mixrow < 0 (row stride = K)
  const float* W;      // (N, K) row-major
  float* out;          // (M, N) row-major
  const float* bias;   // per-n bias or nullptr
  int N, K;
  int mixrow;          // >=0: A = token-shift mix of hidden_states with x_mix[mixrow]
  int ep;              // 0 none, 1 tanh, 2 sigmoid(x+bias?), 3 DECAY*sigmoid(x+bias)
};

__device__ __forceinline__ float4 ld4(const float* p){ return *reinterpret_cast<const float4*>(p); }
__device__ __forceinline__ float sigmf(float x){ return 1.f/(1.f+expf(-x)); }

__device__ __forceinline__ float wredsum(float x){
  #pragma unroll
  for (int off=32; off>0; off>>=1) x += __shfl_xor(x, off);
  return x;
}

#define BM 64
#define BN 128
#define BK 32

// out[m,n] = sum_k A[m,k]*W[n,k]; blockIdx.z selects descriptor (batched launches).
__global__ __launch_bounds__(256) void gemm_kernel(
    GemmDesc d0, GemmDesc d1, GemmDesc d2, GemmDesc d3,
    const float* __restrict__ xmix, const float* __restrict__ hs)
{
  GemmDesc d = (blockIdx.z==0)?d0:(blockIdx.z==1)?d1:(blockIdx.z==2)?d2:d3;
  const int n0 = blockIdx.x * BN;
  if (n0 >= d.N) return;            // block-uniform
  const int m0 = blockIdx.y * BM;
  const int tid = threadIdx.x;
  __shared__ float As[BK][BM+4];
  __shared__ float Bs[BK][BN+4];
  const int ty = tid >> 4, tx = tid & 15;

  float acc[4][8];
  #pragma unroll
  for (int i=0;i<4;++i)
    #pragma unroll
    for (int j=0;j<8;++j) acc[i][j]=0.f;

  const int K = d.K;
  const int nt = K / BK;
  const float* mrow = (d.mixrow >= 0) ? (xmix + (size_t)d.mixrow * Cc) : nullptr;
  float4 pa[2], pb[4];

  auto load_tile = [&](int kt){
    const int kbase = kt * BK;
    #pragma unroll
    for (int u=0;u<2;++u){
      const int li = tid + u*256;
      const int ar = li >> 3;
      const int kk = ((li & 7) << 2) + kbase;
      const int gm = m0 + ar;
      if (mrow){
        float4 h0 = ld4(hs + (size_t)gm*Cc + kk);
        float4 mx = ld4(mrow + kk);
        float4 hp = make_float4(0.f,0.f,0.f,0.f);
        if ((gm & (Tt-1)) != 0) hp = ld4(hs + (size_t)(gm-1)*Cc + kk);
        pa[u].x = h0.x + (hp.x - h0.x)*mx.x;
        pa[u].y = h0.y + (hp.y - h0.y)*mx.y;
        pa[u].z = h0.z + (hp.z - h0.z)*mx.z;
        pa[u].w = h0.w + (hp.w - h0.w)*mx.w;
      } else {
        pa[u] = ld4(d.A + (size_t)gm*K + kk);
      }
    }
    #pragma unroll
    for (int u=0;u<4;++u){
      const int li = tid + u*256;
      const int br = li >> 3;
      const int kk = ((li & 7) << 2) + kbase;
      const int gn = n0 + br;
      pb[u] = (gn < d.N) ? ld4(d.W + (size_t)gn*K + kk) : make_float4(0.f,0.f,0.f,0.f);
    }
  };

  load_tile(0);
  for (int kt=0; kt<nt; ++kt){
    __syncthreads();
    #pragma unroll
    for (int u=0;u<2;++u){
      const int li = tid + u*256;
      const int ar = li >> 3;
      const int kc = (li & 7) << 2;
      As[kc+0][ar] = pa[u].x; As[kc+1][ar] = pa[u].y;
      As[kc+2][ar] = pa[u].z; As[kc+3][ar] = pa[u].w;
    }
    #pragma unroll
    for (int u=0;u<4;++u){
      const int li = tid + u*256;
      const int br = li >> 3;
      const int kc = (li & 7) << 2;
      Bs[kc+0][br] = pb[u].x; Bs[kc+1][br] = pb[u].y;
      Bs[kc+2][br] = pb[u].z; Bs[kc+3][br] = pb[u].w;
    }
    __syncthreads();
    if (kt+1 < nt) load_tile(kt+1);
    #pragma unroll
    for (int kk=0;kk<BK;++kk){
      const float4 a0 = *(const float4*)&As[kk][ty<<2];
      const float4 b0 = *(const float4*)&Bs[kk][tx<<3];
      const float4 b1 = *(const float4*)&Bs[kk][(tx<<3)+4];
      const float av[4] = {a0.x,a0.y,a0.z,a0.w};
      const float bv[8] = {b0.x,b0.y,b0.z,b0.w,b1.x,b1.y,b1.z,b1.w};
      #pragma unroll
      for (int i=0;i<4;++i)
        #pragma unroll
        for (int j=0;j<8;++j)
          acc[i][j] = fmaf(av[i], bv[j], acc[i][j]);
    }
  }

  const int ep = d.ep;
  #pragma unroll
  for (int i=0;i<4;++i){
    const int gm = m0 + (ty<<2) + i;
    float* orow = d.out + (size_t)gm * d.N;
    #pragma unroll
    for (int j=0;j<8;++j){
      const int gn = n0 + (tx<<3) + j;
      if (gn < d.N){
        float x = acc[i][j];
        if (ep==1) x = tanhf(x);
        else if (ep==2){ if (d.bias) x += d.bias[gn]; x = sigmf(x); }
        else if (ep==3){ x += d.bias[gn]; x = DECAY_SCALE * sigmf(x); }
        orow[gn] = x;
      }
    }
  }
}

// Per-(token,head) wave: kk = normalize(k0*k_k); v = lerp(v0, v_first, sv); kfin.
__global__ __launch_bounds__(256) void head_prep(
    float* __restrict__ kbuf,        // in: k0, out: kfin
    const float* __restrict__ abuf,  // sigmoid a
    float* __restrict__ kkbuf,       // in: sv (v-lora sigmoid), out: kk normalized
    float* __restrict__ vbuf,        // in: v0, out: v
    const float* __restrict__ vfirst,
    const float* __restrict__ k_k, const float* __restrict__ k_a)
{
  const int gid = blockIdx.x*4 + (threadIdx.x>>6);
  const int e = threadIdx.x & 63;
  const int m = gid >> 4;
  const int h = gid & 15;
  const int c = h*Dd + e;
  const size_t idx = (size_t)m*Cc + c;
  const float kv0 = kbuf[idx];
  const float kku = kv0 * k_k[c];
  const float ss  = wredsum(kku*kku);
  const float kkn = kku / fmaxf(sqrtf(ss), 1e-12f);
  const float sv  = kkbuf[idx];
  const float vf  = vfirst[idx];
  const float v0  = vbuf[idx];
  const float av  = abuf[idx];
  kkbuf[idx] = kkn;
  vbuf[idx]  = v0 + sv*(vf - v0);
  kbuf[idx]  = kv0 * (1.f + (av - 1.f)*k_a[c]);
}

// Sequential scan v2: one block per (b,h); 4 independent waves (wave w = columns
// 16w..16w+15, lane = rh*16+el owns rows rh*16..rh*16+15 of column e).
// Coefficients batch-staged to LDS 16 steps at a time: barriers amortized 2/16,
// next batch's global loads issued AFTER the staging barrier so the vmcnt drain
// at the next barrier is free (loads complete under ~5000 cyc of compute).
__global__ __launch_bounds__(256) void scan_kernel(
    const float* __restrict__ wl, const float* __restrict__ kb,
    const float* __restrict__ vb, const float* __restrict__ rb,
    const float* __restrict__ kkb, const float* __restrict__ ab,
    float* __restrict__ outp)
{
  const int bh = blockIdx.x;
  const int b = bh >> 4, h = bh & 15;
  const int tid  = threadIdx.x;
  const int wave = tid >> 6;
  const int lane = tid & 63;
  const int el = lane & 15;
  const int rh = lane >> 4;
  const int e  = (wave<<4) + el;

  // LDS: per 16-step batch. Pair-packed coefficient quads with rh-skew (row
  // stride 36 float4 = 4 rh-groups * 9) so the 4-distinct-address 16-way
  // broadcast reads in the step loop are bank-conflict-free.
  __shared__ float4 CAl[16*36];             // (law0,ew0,law1,ew1) pairs
  __shared__ float4 CBl[16*36];             // (bb0,k0,bb1,k1) pairs
  __shared__ float4 Rl[16*16];              // r quads
  __shared__ __align__(16) float Vl[16*64]; // v

  float S[16];
  #pragma unroll
  for (int j=0;j<16;++j) S[j]=0.f;

  const size_t base = ((size_t)b*Tt)*Cc + h*Dd;

  // staging role: row g (timestep within batch), float4 column i4
  const int g  = tid >> 4;
  const int i4 = tid & 15;

  float4 pw, pkk, pa, pk, pr, pv;
  auto prefetch = [&](int batch){
    if (batch < Tt/16){
      const size_t off = base + (size_t)(batch*16 + g)*Cc + i4*4;
      pw  = ld4(wl + off);  pkk = ld4(kkb + off); pa = ld4(ab + off);
      pk  = ld4(kb + off);  pr  = ld4(rb + off);  pv = ld4(vb + off);
    }
  };
  prefetch(0);

  for (int batch = 0; batch < Tt/16; ++batch){
    __syncthreads();   // previous batch's compute done -> LDS reusable
    {
      const float ew0 = expf(pw.x), ew1 = expf(pw.y);
      const float ew2 = expf(pw.z), ew3 = expf(pw.w);
      const int sb = g*36 + (i4>>2)*9 + ((2*i4)&7);
      CAl[sb]   = make_float4(-pkk.x*ew0, ew0, -pkk.y*ew1, ew1);
      CAl[sb+1] = make_float4(-pkk.z*ew2, ew2, -pkk.w*ew3, ew3);
      CBl[sb]   = make_float4(pkk.x*pa.x, pk.x, pkk.y*pa.y, pk.y);
      CBl[sb+1] = make_float4(pkk.z*pa.z, pk.z, pkk.w*pa.w, pk.w);
      Rl[g*16 + i4] = pr;
      *(float4*)&Vl[g*64 + i4*4] = pv;
    }
    __syncthreads();   // staging visible
    prefetch(batch+1); // in-flight during compute; drained (free) at next barrier

    for (int j = 0; j < 16; ++j){
      const float vv = Vl[j*64 + e];
      const int ca = j*36 + rh*9;
      float ta = 0.f, tb = 0.f;
      #pragma unroll
      for (int p=0;p<8;++p){
        const float4 q = CAl[ca + p];
        ta = fmaf(q.x, S[2*p],   ta); S[2*p]   *= q.y;
        tb = fmaf(q.z, S[2*p+1], tb); S[2*p+1] *= q.w;
      }
      ta += tb;
      ta += __shfl_xor(ta, 16);
      ta += __shfl_xor(ta, 32);
      #pragma unroll
      for (int p=0;p<8;++p){
        const float4 q = CBl[ca + p];
        S[2*p]   = fmaf(q.x, ta, fmaf(q.y, vv, S[2*p]));
        S[2*p+1] = fmaf(q.z, ta, fmaf(q.w, vv, S[2*p+1]));
      }
      float oe = 0.f, ob = 0.f;
      #pragma unroll
      for (int q=0;q<4;++q){
        const float4 r4 = Rl[j*16 + rh*4 + q];
        oe = fmaf(r4.x, S[4*q],   oe); ob = fmaf(r4.y, S[4*q+1], ob);
        oe = fmaf(r4.z, S[4*q+2], oe); ob = fmaf(r4.w, S[4*q+3], ob);
      }
      oe += ob;
      oe += __shfl_xor(oe, 16);
      oe += __shfl_xor(oe, 32);
      if (rh == 0) outp[base + (size_t)(batch*16 + j)*Cc + e] = oe;
    }
  }
}

// GroupNorm per head + correction + g gating -> o_pre
__global__ __launch_bounds__(256) void epilogue_kernel(
    const float* __restrict__ att, const float* __restrict__ rbuf,
    const float* __restrict__ kbuf, const float* __restrict__ vbuf,
    const float* __restrict__ gbuf,
    const float* __restrict__ r_k, const float* __restrict__ gn_w,
    const float* __restrict__ gn_b, float* __restrict__ opre)
{
  const int gid = blockIdx.x*4 + (threadIdx.x>>6);
  const int e = threadIdx.x & 63;
  const int m = gid >> 4;
  const int h = gid & 15;
  const int c = h*Dd + e;
  const size_t idx = (size_t)m*Cc + c;
  const float x  = att[idx];
  const float mu = wredsum(x) * (1.f/Dd);
  const float xd = x - mu;
  const float var = wredsum(xd*xd) * (1.f/Dd);
  const float og = xd * (1.f/sqrtf(var + GN_EPS)) * gn_w[c] + gn_b[c];
  const float rv = rbuf[idx], kv = kbuf[idx], vv = vbuf[idx];
  const float cd = wredsum(rv*kv*r_k[c]);
  opre[idx] = (og + cd*vv) * gbuf[idx];
}

extern "C" void kernel_launch(void* const* d_in, const int* in_sizes, int n_in,
                              void* d_out, int out_size, void* d_ws, size_t ws_size,
                              hipStream_t stream)
{
  (void)in_sizes; (void)n_in; (void)out_size; (void)ws_size;
  const float* hs     = (const float*)d_in[0];
  const float* vfirst = (const float*)d_in[1];
  const float* xmix   = (const float*)d_in[2];
  const float* k_k    = (const float*)d_in[3];
  const float* k_a    = (const float*)d_in[4];
  const float* r_k    = (const float*)d_in[5];
  const float* W_r    = (const float*)d_in[6];
  const float* W_k    = (const float*)d_in[7];
  const float* W_v    = (const float*)d_in[8];
  const float* W_o    = (const float*)d_in[9];
  const float* w_A    = (const float*)d_in[10];
  const float* w_B    = (const float*)d_in[11];
  const float* w_b    = (const float*)d_in[12];
  const float* a_A    = (const float*)d_in[13];
  const float* a_B    = (const float*)d_in[14];
  const float* a_b    = (const float*)d_in[15];
  const float* v_A    = (const float*)d_in[16];
  const float* v_B    = (const float*)d_in[17];
  const float* v_b    = (const float*)d_in[18];
  const float* g_A    = (const float*)d_in[19];
  const float* g_B    = (const float*)d_in[20];
  const float* gn_w   = (const float*)d_in[21];
  const float* gn_b   = (const float*)d_in[22];
  float* out = (float*)d_out;
  float* ws  = (float*)d_ws;

  const size_t MC = (size_t)Mm * Cc;
  float* Br   = ws;            // r
  float* Bw   = ws + MC;       // w log-decay  -> later o_pre
  float* Bk   = ws + 2*MC;     // k0 -> kfin
  float* Bkk  = ws + 3*MC;     // sv -> kk
  float* Bv   = ws + 4*MC;     // v0 -> v
  float* Ba   = ws + 5*MC;     // a (sigmoid)
  float* Batt = ws + 6*MC;     // scan output
  float* Bg   = ws + 7*MC;     // g
  float* T1w  = ws + 8*MC;
  float* T1a  = T1w + (size_t)Mm*64;
  float* T1v  = T1a + (size_t)Mm*64;
  float* T1g  = T1v + (size_t)Mm*64;   // Mm*160

  dim3 blk(256,1,1);

  // L1: big projections r, k0, v0 (batched over z)
  GemmDesc dr{nullptr, W_r, Br, nullptr, Cc, Cc, 0, 0};
  GemmDesc dk{nullptr, W_k, Bk, nullptr, Cc, Cc, 2, 0};
  GemmDesc dv{nullptr, W_v, Bv, nullptr, Cc, Cc, 3, 0};
  gemm_kernel<<<dim3(8,32,3), blk, 0, stream>>>(dr,dk,dv,dr, xmix, hs);

  // L2: LoRA stage-1 (w: tanh; a: none; v: none; g: sigmoid)
  GemmDesc s1w{nullptr, w_A, T1w, nullptr, 64, Cc, 1, 1};
  GemmDesc s1a{nullptr, a_A, T1a, nullptr, 64, Cc, 4, 0};
  GemmDesc s1v{nullptr, v_A, T1v, nullptr, 64, Cc, 3, 0};
  GemmDesc s1g{nullptr, g_A, T1g, nullptr, 160, Cc, 5, 2};
  gemm_kernel<<<dim3(2,32,4), blk, 0, stream>>>(s1w,s1a,s1v,s1g, xmix, hs);

  // L3: LoRA stage-2
  GemmDesc s2w{T1w, w_B, Bw,  w_b,    Cc, 64,  -1, 3};
  GemmDesc s2a{T1a, a_B, Ba,  a_b,    Cc, 64,  -1, 2};
  GemmDesc s2v{T1v, v_B, Bkk, v_b,    Cc, 64,  -1, 2};
  GemmDesc s2g{T1g, g_B, Bg,  nullptr,Cc, 160, -1, 0};
  gemm_kernel<<<dim3(8,32,4), blk, 0, stream>>>(s2w,s2a,s2v,s2g, xmix, hs);

  // L4: per-head prep (kk normalize, v lerp, kfin)
  head_prep<<<dim3(Mm*Hh/4), blk, 0, stream>>>(Bk, Ba, Bkk, Bv, vfirst, k_k, k_a);

  // L5: sequential scan (v2: batch-staged coefficients, 2 barriers / 16 steps)
  scan_kernel<<<dim3(Bb*Hh), blk, 0, stream>>>(Bw, Bk, Bv, Br, Bkk, Ba, Batt);

  // L6: groupnorm + corr + g -> o_pre (reuse Bw)
  epilogue_kernel<<<dim3(Mm*Hh/4), blk, 0, stream>>>(Batt, Br, Bk, Bv, Bg,
                                                     r_k, gn_w, gn_b, Bw);

  // L7: output projection
  GemmDesc doo{Bw, W_o, out, nullptr, Cc, Cc, -1, 0};
  gemm_kernel<<<dim3(8,32,1), blk, 0, stream>>>(doo,doo,doo,doo, xmix, hs);
}

// Round 3
// 869.415 us; speedup vs baseline: 1.6051x; 1.2124x over previous
//
#include <hip/hip_runtime.h>
#include <math.h>

#define Bb 2
#define Tt 1024
#define Cc 1024
#define Hh 16
#define Dd 64
#define Mm (Bb*Tt)
#define DECAY_SCALE (-0.6065306597126334f)
#define GN_EPS (64e-5f)

struct GemmDesc {
  const float* A;      // used when mixrow < 0 (row stride = K)
  const float* W;      // (N, K) row-major
  float* out;          // (M, N) row-major
  const float* bias;   // per-n bias or nullptr
  int N, K;
  int mixrow;          // >=0: A = token-shift mix of hidden_states with x_mix[mixrow]
  int ep;              // 0 none, 1 tanh, 2 sigmoid(x+bias?), 3 DECAY*sigmoid(x+bias)
};

__device__ __forceinline__ float4 ld4(const float* p){ return *reinterpret_cast<const float4*>(p); }
__device__ __forceinline__ float sigmf(float x){ return 1.f/(1.f+expf(-x)); }

__device__ __forceinline__ float wredsum(float x){
  #pragma unroll
  for (int off=32; off>0; off>>=1) x += __shfl_xor(x, off);
  return x;
}

#define BM 64
#define BN 128
#define BK 32

// out[m,n] = sum_k A[m,k]*W[n,k]; blockIdx.z selects descriptor (batched launches).
__global__ __launch_bounds__(256) void gemm_kernel(
    GemmDesc d0, GemmDesc d1, GemmDesc d2, GemmDesc d3,
    const float* __restrict__ xmix, const float* __restrict__ hs)
{
  GemmDesc d = (blockIdx.z==0)?d0:(blockIdx.z==1)?d1:(blockIdx.z==2)?d2:d3;
  const int n0 = blockIdx.x * BN;
  if (n0 >= d.N) return;            // block-uniform
  const int m0 = blockIdx.y * BM;
  const int tid = threadIdx.x;
  __shared__ float As[BK][BM+4];
  __shared__ float Bs[BK][BN+4];
  const int ty = tid >> 4, tx = tid & 15;

  float acc[4][8];
  #pragma unroll
  for (int i=0;i<4;++i)
    #pragma unroll
    for (int j=0;j<8;++j) acc[i][j]=0.f;

  const int K = d.K;
  const int nt = K / BK;
  const float* mrow = (d.mixrow >= 0) ? (xmix + (size_t)d.mixrow * Cc) : nullptr;
  float4 pa[2], pb[4];

  auto load_tile = [&](int kt){
    const int kbase = kt * BK;
    #pragma unroll
    for (int u=0;u<2;++u){
      const int li = tid + u*256;
      const int ar = li >> 3;
      const int kk = ((li & 7) << 2) + kbase;
      const int gm = m0 + ar;
      if (mrow){
        float4 h0 = ld4(hs + (size_t)gm*Cc + kk);
        float4 mx = ld4(mrow + kk);
        float4 hp = make_float4(0.f,0.f,0.f,0.f);
        if ((gm & (Tt-1)) != 0) hp = ld4(hs + (size_t)(gm-1)*Cc + kk);
        pa[u].x = h0.x + (hp.x - h0.x)*mx.x;
        pa[u].y = h0.y + (hp.y - h0.y)*mx.y;
        pa[u].z = h0.z + (hp.z - h0.z)*mx.z;
        pa[u].w = h0.w + (hp.w - h0.w)*mx.w;
      } else {
        pa[u] = ld4(d.A + (size_t)gm*K + kk);
      }
    }
    #pragma unroll
    for (int u=0;u<4;++u){
      const int li = tid + u*256;
      const int br = li >> 3;
      const int kk = ((li & 7) << 2) + kbase;
      const int gn = n0 + br;
      pb[u] = (gn < d.N) ? ld4(d.W + (size_t)gn*K + kk) : make_float4(0.f,0.f,0.f,0.f);
    }
  };

  load_tile(0);
  for (int kt=0; kt<nt; ++kt){
    __syncthreads();
    #pragma unroll
    for (int u=0;u<2;++u){
      const int li = tid + u*256;
      const int ar = li >> 3;
      const int kc = (li & 7) << 2;
      As[kc+0][ar] = pa[u].x; As[kc+1][ar] = pa[u].y;
      As[kc+2][ar] = pa[u].z; As[kc+3][ar] = pa[u].w;
    }
    #pragma unroll
    for (int u=0;u<4;++u){
      const int li = tid + u*256;
      const int br = li >> 3;
      const int kc = (li & 7) << 2;
      Bs[kc+0][br] = pb[u].x; Bs[kc+1][br] = pb[u].y;
      Bs[kc+2][br] = pb[u].z; Bs[kc+3][br] = pb[u].w;
    }
    __syncthreads();
    if (kt+1 < nt) load_tile(kt+1);
    #pragma unroll
    for (int kk=0;kk<BK;++kk){
      const float4 a0 = *(const float4*)&As[kk][ty<<2];
      const float4 b0 = *(const float4*)&Bs[kk][tx<<3];
      const float4 b1 = *(const float4*)&Bs[kk][(tx<<3)+4];
      const float av[4] = {a0.x,a0.y,a0.z,a0.w};
      const float bv[8] = {b0.x,b0.y,b0.z,b0.w,b1.x,b1.y,b1.z,b1.w};
      #pragma unroll
      for (int i=0;i<4;++i)
        #pragma unroll
        for (int j=0;j<8;++j)
          acc[i][j] = fmaf(av[i], bv[j], acc[i][j]);
    }
  }

  const int ep = d.ep;
  #pragma unroll
  for (int i=0;i<4;++i){
    const int gm = m0 + (ty<<2) + i;
    float* orow = d.out + (size_t)gm * d.N;
    #pragma unroll
    for (int j=0;j<8;++j){
      const int gn = n0 + (tx<<3) + j;
      if (gn < d.N){
        float x = acc[i][j];
        if (ep==1) x = tanhf(x);
        else if (ep==2){ if (d.bias) x += d.bias[gn]; x = sigmf(x); }
        else if (ep==3){ x += d.bias[gn]; x = DECAY_SCALE * sigmf(x); }
        orow[gn] = x;
      }
    }
  }
}

// Per-(token,head) wave. Reads k0/a/sv/w/v0; writes (IN PLACE on dead inputs):
//   kbuf: k0 -> kfin;  awbuf: a -> ew=exp(w);  svwbuf: sv -> law=-kk*ew;
//   wbbuf: w -> bb=kk*a;  vbuf: v0 -> lerp(v0, v_first, sv).
// Per-thread read-before-write on the SAME index => alias-safe.
__global__ __launch_bounds__(256) void head_prep(
    float* kbuf, float* awbuf, float* svwbuf, float* wbbuf, float* vbuf,
    const float* __restrict__ vfirst,
    const float* __restrict__ k_k, const float* __restrict__ k_a)
{
  const int gid = blockIdx.x*4 + (threadIdx.x>>6);
  const int e = threadIdx.x & 63;
  const int m = gid >> 4;
  const int h = gid & 15;
  const int c = h*Dd + e;
  const size_t idx = (size_t)m*Cc + c;
  const float kv0 = kbuf[idx];
  const float av  = awbuf[idx];
  const float sv  = svwbuf[idx];
  const float wv  = wbbuf[idx];
  const float v0  = vbuf[idx];
  const float vf  = vfirst[idx];
  const float kku = kv0 * k_k[c];
  const float ss  = wredsum(kku*kku);
  const float kkn = kku / fmaxf(sqrtf(ss), 1e-12f);
  const float ew  = expf(wv);
  kbuf[idx]  = kv0 * (1.f + (av - 1.f)*k_a[c]);
  awbuf[idx] = ew;
  svwbuf[idx]= -kkn * ew;
  wbbuf[idx] = kkn * av;
  vbuf[idx]  = v0 + sv*(vf - v0);
}

// Sequential scan v3: 8 blocks of ONE wave (64 thr) per (b,h) chain -> 256
// blocks ~= 1/CU: 8x the LDS pipes vs v2 and no intra-CU wave contention.
// Block owns 8 columns; lane = rg*8+cs owns rows rg*8..rg*8+7 of column cs.
// Coefficients (law, ew, bb, k, r) staged 16 steps/batch into skewed LDS
// (stride 19 float4 per step: 8 rg-addresses hit disjoint bank groups).
// Per step: 11 LDS reads (41 dwords) + 6 shfl + ~56 VALU.
#define SST 19   // float4 stride per step for row-coefficient arrays
__global__ __launch_bounds__(64) void scan_kernel(
    const float* __restrict__ lawb, const float* __restrict__ ewb,
    const float* __restrict__ bbb,  const float* __restrict__ kb,
    const float* __restrict__ rb,   const float* __restrict__ vb,
    float* __restrict__ outp)
{
  const int blk  = blockIdx.x;
  const int bh   = blk & 31;        // chain's 8 blocks are %32-congruent -> same XCD
  const int blkc = blk >> 5;        // 0..7: column-octet within head
  const int b = bh >> 4, h = bh & 15;
  const int lane = threadIdx.x;
  const int cs = lane & 7;          // column slot
  const int rg = lane >> 3;         // row group (8 rows)
  const int c0 = blkc * 8;

  __shared__ float4 Ll[16*SST];     // law
  __shared__ float4 El[16*SST];     // ew
  __shared__ float4 Bl[16*SST];     // bb
  __shared__ float4 Kl[16*SST];     // k
  __shared__ float4 Rl[16*SST];     // r
  __shared__ float  Vl[16*8];       // v (block's 8 columns)

  float S[8];
  #pragma unroll
  for (int j=0;j<8;++j) S[j]=0.f;

  const size_t mbase = (size_t)b*Tt;
  const int g = lane >> 2, q = lane & 3;   // staging: step g, quad q

  float4 pl[4], pe[4], pb4[4], pk[4], pr[4];
  float pv[2];
  auto prefetch = [&](int batch){
    if (batch < Tt/16){
      const size_t m0 = mbase + (size_t)batch*16;
      const size_t rowb = (m0 + g)*Cc + h*Dd;
      #pragma unroll
      for (int u=0;u<4;++u){
        const size_t o = rowb + (q + 4*u)*4;
        pl[u]  = ld4(lawb + o);
        pe[u]  = ld4(ewb  + o);
        pb4[u] = ld4(bbb  + o);
        pk[u]  = ld4(kb   + o);
        pr[u]  = ld4(rb   + o);
      }
      #pragma unroll
      for (int u=0;u<2;++u){
        const int idx = lane + 64*u;
        pv[u] = vb[(m0 + (idx>>3))*Cc + h*Dd + c0 + (idx&7)];
      }
    }
  };
  prefetch(0);

  for (int batch = 0; batch < Tt/16; ++batch){
    __syncthreads();   // previous batch's compute done -> LDS reusable
    #pragma unroll
    for (int u=0;u<4;++u){
      const int q4 = q + 4*u;                 // float4 index within row (rows 4q4..4q4+3)
      const int rw = q4 >> 1, pw = q4 & 1;    // row-group, half
      const int ad = g*SST + rw*2 + pw + (rw>>2);
      Ll[ad] = pl[u]; El[ad] = pe[u]; Bl[ad] = pb4[u];
      Kl[ad] = pk[u]; Rl[ad] = pr[u];
    }
    #pragma unroll
    for (int u=0;u<2;++u){
      const int idx = lane + 64*u;
      Vl[(idx>>3)*8 + (idx&7)] = pv[u];
    }
    __syncthreads();   // staging visible
    prefetch(batch+1); // loads in flight under ~3000 cyc of compute

    #pragma unroll 2
    for (int j = 0; j < 16; ++j){
      const float vv = Vl[j*8 + cs];
      const int a0 = j*SST + rg*2 + (rg>>2);
      const float4 l0 = Ll[a0], l1 = Ll[a0+1];
      const float4 e0 = El[a0], e1 = El[a0+1];
      float ta = 0.f, tb = 0.f;
      ta = fmaf(l0.x, S[0], ta); tb = fmaf(l0.y, S[1], tb);
      ta = fmaf(l0.z, S[2], ta); tb = fmaf(l0.w, S[3], tb);
      ta = fmaf(l1.x, S[4], ta); tb = fmaf(l1.y, S[5], tb);
      ta = fmaf(l1.z, S[6], ta); tb = fmaf(l1.w, S[7], tb);
      S[0]*=e0.x; S[1]*=e0.y; S[2]*=e0.z; S[3]*=e0.w;
      S[4]*=e1.x; S[5]*=e1.y; S[6]*=e1.z; S[7]*=e1.w;
      ta += tb;
      ta += __shfl_xor(ta, 8);
      ta += __shfl_xor(ta, 16);
      ta += __shfl_xor(ta, 32);
      const float4 b0 = Bl[a0], b1 = Bl[a0+1];
      const float4 k0 = Kl[a0], k1 = Kl[a0+1];
      S[0] = fmaf(b0.x, ta, fmaf(k0.x, vv, S[0]));
      S[1] = fmaf(b0.y, ta, fmaf(k0.y, vv, S[1]));
      S[2] = fmaf(b0.z, ta, fmaf(k0.z, vv, S[2]));
      S[3] = fmaf(b0.w, ta, fmaf(k0.w, vv, S[3]));
      S[4] = fmaf(b1.x, ta, fmaf(k1.x, vv, S[4]));
      S[5] = fmaf(b1.y, ta, fmaf(k1.y, vv, S[5]));
      S[6] = fmaf(b1.z, ta, fmaf(k1.z, vv, S[6]));
      S[7] = fmaf(b1.w, ta, fmaf(k1.w, vv, S[7]));
      const float4 r0 = Rl[a0], r1 = Rl[a0+1];
      float oe = 0.f, ob = 0.f;
      oe = fmaf(r0.x, S[0], oe); ob = fmaf(r0.y, S[1], ob);
      oe = fmaf(r0.z, S[2], oe); ob = fmaf(r0.w, S[3], ob);
      oe = fmaf(r1.x, S[4], oe); ob = fmaf(r1.y, S[5], ob);
      oe = fmaf(r1.z, S[6], oe); ob = fmaf(r1.w, S[7], ob);
      oe += ob;
      oe += __shfl_xor(oe, 8);
      oe += __shfl_xor(oe, 16);
      oe += __shfl_xor(oe, 32);
      if (rg == 0)
        outp[(mbase + (size_t)(batch*16 + j))*Cc + h*Dd + c0 + cs] = oe;
    }
  }
}

// GroupNorm per head + correction + g gating -> o_pre
__global__ __launch_bounds__(256) void epilogue_kernel(
    const float* __restrict__ att, const float* __restrict__ rbuf,
    const float* __restrict__ kbuf, const float* __restrict__ vbuf,
    const float* __restrict__ gbuf,
    const float* __restrict__ r_k, const float* __restrict__ gn_w,
    const float* __restrict__ gn_b, float* __restrict__ opre)
{
  const int gid = blockIdx.x*4 + (threadIdx.x>>6);
  const int e = threadIdx.x & 63;
  const int m = gid >> 4;
  const int h = gid & 15;
  const int c = h*Dd + e;
  const size_t idx = (size_t)m*Cc + c;
  const float x  = att[idx];
  const float mu = wredsum(x) * (1.f/Dd);
  const float xd = x - mu;
  const float var = wredsum(xd*xd) * (1.f/Dd);
  const float og = xd * (1.f/sqrtf(var + GN_EPS)) * gn_w[c] + gn_b[c];
  const float rv = rbuf[idx], kv = kbuf[idx], vv = vbuf[idx];
  const float cd = wredsum(rv*kv*r_k[c]);
  opre[idx] = (og + cd*vv) * gbuf[idx];
}

extern "C" void kernel_launch(void* const* d_in, const int* in_sizes, int n_in,
                              void* d_out, int out_size, void* d_ws, size_t ws_size,
                              hipStream_t stream)
{
  (void)in_sizes; (void)n_in; (void)out_size; (void)ws_size;
  const float* hs     = (const float*)d_in[0];
  const float* vfirst = (const float*)d_in[1];
  const float* xmix   = (const float*)d_in[2];
  const float* k_k    = (const float*)d_in[3];
  const float* k_a    = (const float*)d_in[4];
  const float* r_k    = (const float*)d_in[5];
  const float* W_r    = (const float*)d_in[6];
  const float* W_k    = (const float*)d_in[7];
  const float* W_v    = (const float*)d_in[8];
  const float* W_o    = (const float*)d_in[9];
  const float* w_A    = (const float*)d_in[10];
  const float* w_B    = (const float*)d_in[11];
  const float* w_b    = (const float*)d_in[12];
  const float* a_A    = (const float*)d_in[13];
  const float* a_B    = (const float*)d_in[14];
  const float* a_b    = (const float*)d_in[15];
  const float* v_A    = (const float*)d_in[16];
  const float* v_B    = (const float*)d_in[17];
  const float* v_b    = (const float*)d_in[18];
  const float* g_A    = (const float*)d_in[19];
  const float* g_B    = (const float*)d_in[20];
  const float* gn_w   = (const float*)d_in[21];
  const float* gn_b   = (const float*)d_in[22];
  float* out = (float*)d_out;
  float* ws  = (float*)d_ws;

  const size_t MC = (size_t)Mm * Cc;
  float* Br   = ws;            // r
  float* Bw   = ws + MC;       // w -> bb (head_prep) -> o_pre (epilogue)
  float* Bk   = ws + 2*MC;     // k0 -> kfin
  float* Bkk  = ws + 3*MC;     // sv -> law
  float* Bv   = ws + 4*MC;     // v0 -> v
  float* Ba   = ws + 5*MC;     // a -> ew
  float* Batt = ws + 6*MC;     // scan output
  float* Bg   = ws + 7*MC;     // g
  float* T1w  = ws + 8*MC;
  float* T1a  = T1w + (size_t)Mm*64;
  float* T1v  = T1a + (size_t)Mm*64;
  float* T1g  = T1v + (size_t)Mm*64;   // Mm*160

  dim3 blk(256,1,1);

  // L1: big projections r, k0, v0 (batched over z)
  GemmDesc dr{nullptr, W_r, Br, nullptr, Cc, Cc, 0, 0};
  GemmDesc dk{nullptr, W_k, Bk, nullptr, Cc, Cc, 2, 0};
  GemmDesc dv{nullptr, W_v, Bv, nullptr, Cc, Cc, 3, 0};
  gemm_kernel<<<dim3(8,32,3), blk, 0, stream>>>(dr,dk,dv,dr, xmix, hs);

  // L2: LoRA stage-1 (w: tanh; a: none; v: none; g: sigmoid)
  GemmDesc s1w{nullptr, w_A, T1w, nullptr, 64, Cc, 1, 1};
  GemmDesc s1a{nullptr, a_A, T1a, nullptr, 64, Cc, 4, 0};
  GemmDesc s1v{nullptr, v_A, T1v, nullptr, 64, Cc, 3, 0};
  GemmDesc s1g{nullptr, g_A, T1g, nullptr, 160, Cc, 5, 2};
  gemm_kernel<<<dim3(2,32,4), blk, 0, stream>>>(s1w,s1a,s1v,s1g, xmix, hs);

  // L3: LoRA stage-2
  GemmDesc s2w{T1w, w_B, Bw,  w_b,    Cc, 64,  -1, 3};
  GemmDesc s2a{T1a, a_B, Ba,  a_b,    Cc, 64,  -1, 2};
  GemmDesc s2v{T1v, v_B, Bkk, v_b,    Cc, 64,  -1, 2};
  GemmDesc s2g{T1g, g_B, Bg,  nullptr,Cc, 160, -1, 0};
  gemm_kernel<<<dim3(8,32,4), blk, 0, stream>>>(s2w,s2a,s2v,s2g, xmix, hs);

  // L4: per-head prep; converts dead buffers in place:
  //   Bk: k0->kfin, Ba: a->ew, Bkk: sv->law, Bw: w->bb, Bv: v0->v
  head_prep<<<dim3(Mm*Hh/4), blk, 0, stream>>>(Bk, Ba, Bkk, Bw, Bv,
                                               vfirst, k_k, k_a);

  // L5: sequential scan (v3: 256 one-wave blocks, 8 per chain)
  scan_kernel<<<dim3(256), dim3(64), 0, stream>>>(Bkk, Ba, Bw, Bk, Br, Bv, Batt);

  // L6: groupnorm + corr + g -> o_pre (reuse Bw; bb dead after scan)
  epilogue_kernel<<<dim3(Mm*Hh/4), blk, 0, stream>>>(Batt, Br, Bk, Bv, Bg,
                                                     r_k, gn_w, gn_b, Bw);

  // L7: output projection
  GemmDesc doo{Bw, W_o, out, nullptr, Cc, Cc, -1, 0};
  gemm_kernel<<<dim3(8,32,1), blk, 0, stream>>>(doo,doo,doo,doo, xmix, hs);
}